// Round 1
// baseline (5053.843 us; speedup 1.0000x reference)
//
#include <hip/hip_runtime.h>
#include <math.h>

#define B_ 32
#define T_ 3000
#define C_ 512
#define THf 1.0f

// ---- ws layout (bytes) ----
// Wt    [5][512][512] f32 : off 0,        5,242,880 B
// alpha [B_*T_]       f32 : off 5242880,    384,000 B
// seg_i [B_*T_]      int2 : off 5626880,    768,000 B
// seg_w [B_*T_]    float2 : off 6394880,    768,000 B
// tot   [B_]          int : off 7162880
#define WT_OFF    0
#define ALPHA_OFF 5242880
#define SEGI_OFF  5626880
#define SEGW_OFF  6394880
#define TOT_OFF   7162880

#define CS_SIZE  ((size_t)B_ * T_ * C_)          // 49,152,000
#define MASK_OFF CS_SIZE                          // B_*T_ floats
#define LOSS_OFF (CS_SIZE + (size_t)B_ * T_)      // 1 float

// ---------------- kernel T: transpose conv_w [o][i][k] -> Wt [k][i][o] ----
__global__ __launch_bounds__(256) void transpose_w_kernel(
    const float* __restrict__ W, float* __restrict__ Wt)
{
    int idx = blockIdx.x * 256 + threadIdx.x;   // idx = ((k*512)+i)*512 + o
    if (idx >= 5 * 512 * 512) return;
    int o = idx & 511;
    int i = (idx >> 9) & 511;
    int k = idx >> 18;
    Wt[idx] = W[o * 2560 + i * 5 + k];
}

// ---------------- kernel A: conv + relu + linear + sigmoid -> alpha --------
// tile: 24 t per block, 256 threads. thread = (tgrp 0..7 -> 3 t) x (ogrp 0..31 -> 16 o)
#define TT   24
#define ROWS 28
#define LDSW 516

__global__ __launch_bounds__(256) void conv_alpha_kernel(
    const float* __restrict__ hs, const float* __restrict__ Wt,
    const float* __restrict__ conv_b, const float* __restrict__ lin_w,
    const float* __restrict__ lin_b, float* __restrict__ alpha)
{
    __shared__ float lds[ROWS * LDSW];   // 57,792 B
    int blk  = blockIdx.x;
    int b    = blk / 125;
    int tile = blk % 125;
    int t0   = tile * TT;
    int tid  = threadIdx.x;

    const float* hb = hs + (size_t)b * T_ * C_;
    // stage hs rows [t0-2, t0+25] with zero padding at sequence edges
    for (int idx = tid; idx < ROWS * C_; idx += 256) {
        int r = idx >> 9, c = idx & (C_ - 1);
        int g = t0 - 2 + r;
        lds[r * LDSW + c] = (g >= 0 && g < T_) ? hb[(size_t)g * C_ + c] : 0.f;
    }
    __syncthreads();

    int tgrp = tid & 7, ogrp = tid >> 3;
    int tb = tgrp * 3, ob = ogrp * 16;

    float acc0[16], acc1[16], acc2[16];
#pragma unroll
    for (int j = 0; j < 16; ++j) { acc0[j] = 0.f; acc1[j] = 0.f; acc2[j] = 0.f; }

    for (int i = 0; i < C_; ++i) {
#pragma unroll
        for (int k = 0; k < 5; ++k) {
            const float4* wp = (const float4*)(Wt + ((((k << 9) | i) << 9) + ob));
            float w[16];
            *(float4*)(w + 0)  = wp[0];
            *(float4*)(w + 4)  = wp[1];
            *(float4*)(w + 8)  = wp[2];
            *(float4*)(w + 12) = wp[3];
            float h0 = lds[(tb + k) * LDSW + i];
            float h1 = lds[(tb + k + 1) * LDSW + i];
            float h2 = lds[(tb + k + 2) * LDSW + i];
#pragma unroll
            for (int j = 0; j < 16; ++j) {
                acc0[j] = fmaf(h0, w[j], acc0[j]);
                acc1[j] = fmaf(h1, w[j], acc1[j]);
                acc2[j] = fmaf(h2, w[j], acc2[j]);
            }
        }
    }

    // epilogue: +bias, relu, dot with lin_w -> per-thread partials over 16 o's
    float p0 = 0.f, p1 = 0.f, p2 = 0.f;
#pragma unroll
    for (int j = 0; j < 16; ++j) {
        float bo = conv_b[ob + j];
        float lw = lin_w[ob + j];
        p0 += fmaxf(acc0[j] + bo, 0.f) * lw;
        p1 += fmaxf(acc1[j] + bo, 0.f) * lw;
        p2 += fmaxf(acc2[j] + bo, 0.f) * lw;
    }
    __syncthreads();                 // done reading hs region; reuse as scratch
    float* scratch = lds;            // [32][24]
    scratch[ogrp * TT + tb + 0] = p0;
    scratch[ogrp * TT + tb + 1] = p1;
    scratch[ogrp * TT + tb + 2] = p2;
    __syncthreads();
    if (tid < TT) {
        float s = 0.f;
        for (int og = 0; og < 32; ++og) s += scratch[og * TT + tid];
        float logit = s + lin_b[0];
        float al = 1.f / (1.f + expf(-logit));
        alpha[b * T_ + t0 + tid] = al;
    }
}

// ---------------- kernel B: sequential CIF scan (exact fp32 ref semantics) --
__global__ __launch_bounds__(64) void scan_kernel(
    float* __restrict__ alpha, const int* __restrict__ mask,
    int2* __restrict__ seg_i, float2* __restrict__ seg_w,
    int* __restrict__ total_rows, float* __restrict__ out_loss)
{
    int lane = threadIdx.x;
    float lsum = 0.f;
    if (lane < B_) {
        const float4* ap = (const float4*)(alpha + lane * T_);
        const int4*   mp = (const int4*)(mask + lane * T_);
        float* astore = alpha + lane * T_;
        int2*   si = seg_i + lane * T_;
        float2* sw = seg_w + lane * T_;

        float acc = 0.f, leftover = 0.f;
        int nf = 0, prev_t = -1;

        float4 c0 = ap[0], c1 = ap[1];
        int4   m0 = mp[0], m1 = mp[1];
        for (int tc = 0; tc < T_ / 8; ++tc) {
            float4 n0, n1; int4 nm0, nm1;
            if (tc + 1 < T_ / 8) {
                n0 = ap[(tc + 1) * 2]; n1 = ap[(tc + 1) * 2 + 1];
                nm0 = mp[(tc + 1) * 2]; nm1 = mp[(tc + 1) * 2 + 1];
            }
            float av[8] = {c0.x, c0.y, c0.z, c0.w, c1.x, c1.y, c1.z, c1.w};
            int   mv[8] = {m0.x, m0.y, m0.z, m0.w, m1.x, m1.y, m1.z, m1.w};
#pragma unroll
            for (int u = 0; u < 8; ++u) {
                int t = tc * 8 + u;
                float araw = av[u];
                lsum += araw;                      // loss uses pre-mask alpha
                float a = (mv[u] != 0) ? araw : 0.f;
                astore[t] = a;                     // masked alpha for emission
                float acc2 = acc + a;              // exact ref op order
                float a1 = THf - acc;
                if (acc2 >= THf) {
                    si[nf] = make_int2(prev_t, t);
                    sw[nf] = make_float2(leftover, a1);
                    float rem = a - a1;            // ref: a - (th - acc)
                    leftover = rem;
                    acc = rem;
                    prev_t = t;
                    ++nf;
                } else {
                    acc = acc2;
                }
            }
            c0 = n0; c1 = n1; m0 = nm0; m1 = nm1;
        }
        int tot = nf;
        if (acc >= 0.5f * THf) {   // tail emission
            si[nf] = make_int2(prev_t, T_);
            sw[nf] = make_float2(leftover, 0.f);
            ++tot;
        }
        total_rows[lane] = tot;
        lsum = fabsf(lsum);
    }
#pragma unroll
    for (int off = 16; off >= 1; off >>= 1) lsum += __shfl_down(lsum, off);
    if (lane == 0) out_loss[0] = lsum;
}

// ---------------- kernel C: segmented weighted emission + zero fill --------
__global__ __launch_bounds__(128) void emit_kernel(
    const float* __restrict__ hs, const float* __restrict__ alpha,
    const int2* __restrict__ seg_i, const float2* __restrict__ seg_w,
    const int* __restrict__ total_rows, float* __restrict__ out)
{
    int blk = blockIdx.x;
    int b = blk / T_;
    int r = blk % T_;
    int tid = threadIdx.x;

    float4* cs4 = (float4*)(out + ((size_t)b * T_ + r) * C_);
    float* maskp = out + MASK_OFF + (size_t)b * T_ + r;
    int tot = total_rows[b];

    if (r >= tot) {
        float4 z; z.x = 0.f; z.y = 0.f; z.z = 0.f; z.w = 0.f;
        cs4[tid] = z;
        if (tid == 0) *maskp = 0.f;
        return;
    }
    int2   si = seg_i[b * T_ + r];
    float2 sw = seg_w[b * T_ + r];
    const float4* hb = (const float4*)(hs + (size_t)b * T_ * C_);
    const float*  ab = alpha + b * T_;

    float4 acc; acc.x = 0.f; acc.y = 0.f; acc.z = 0.f; acc.w = 0.f;
    int ts = si.x, te = si.y;
    if (ts >= 0) {  // leftover from previous fire step
        float4 h = hb[(size_t)ts * (C_ / 4) + tid];
        acc.x = sw.x * h.x; acc.y = sw.x * h.y; acc.z = sw.x * h.z; acc.w = sw.x * h.w;
    }
    for (int t = ts + 1; t < te; ++t) {   // interior: weight = masked alpha
        float a = ab[t];
        float4 h = hb[(size_t)t * (C_ / 4) + tid];
        acc.x = fmaf(a, h.x, acc.x); acc.y = fmaf(a, h.y, acc.y);
        acc.z = fmaf(a, h.z, acc.z); acc.w = fmaf(a, h.w, acc.w);
    }
    if (te < T_) {  // firing step: weight = a1
        float4 h = hb[(size_t)te * (C_ / 4) + tid];
        acc.x = fmaf(sw.y, h.x, acc.x); acc.y = fmaf(sw.y, h.y, acc.y);
        acc.z = fmaf(sw.y, h.z, acc.z); acc.w = fmaf(sw.y, h.w, acc.w);
    }
    cs4[tid] = acc;
    if (tid == 0) *maskp = 1.f;
}

// ---------------- launch ---------------------------------------------------
extern "C" void kernel_launch(void* const* d_in, const int* in_sizes, int n_in,
                              void* d_out, int out_size, void* d_ws, size_t ws_size,
                              hipStream_t stream)
{
    const float* hs     = (const float*)d_in[0];
    const int*   hmask  = (const int*)d_in[1];
    const float* conv_w = (const float*)d_in[2];
    const float* conv_b = (const float*)d_in[3];
    const float* lin_w  = (const float*)d_in[4];
    const float* lin_b  = (const float*)d_in[5];
    float* out = (float*)d_out;
    char*  ws  = (char*)d_ws;

    float*  Wt    = (float*)(ws + WT_OFF);
    float*  alpha = (float*)(ws + ALPHA_OFF);
    int2*   seg_i = (int2*)(ws + SEGI_OFF);
    float2* seg_w = (float2*)(ws + SEGW_OFF);
    int*    tot   = (int*)(ws + TOT_OFF);

    transpose_w_kernel<<<(5 * 512 * 512 + 255) / 256, 256, 0, stream>>>(conv_w, Wt);
    conv_alpha_kernel<<<B_ * 125, 256, 0, stream>>>(hs, Wt, conv_b, lin_w, lin_b, alpha);
    scan_kernel<<<1, 64, 0, stream>>>(alpha, hmask, seg_i, seg_w, tot, out + LOSS_OFF);
    emit_kernel<<<B_ * T_, 128, 0, stream>>>(hs, alpha, seg_i, seg_w, tot, out);
}

// Round 2
// 1131.594 us; speedup vs baseline: 4.4661x; 4.4661x over previous
//
#include <hip/hip_runtime.h>
#include <math.h>

#define B_ 32
#define T_ 3000
#define C_ 512
#define THf 1.0f
#define KW 2560   // 5*512 flattened conv K

typedef _Float16 f16;
typedef _Float16 half8 __attribute__((ext_vector_type(8)));
typedef _Float16 half4 __attribute__((ext_vector_type(4)));
typedef float floatx4 __attribute__((ext_vector_type(4)));

// ---- ws layout (bytes) ----
#define WHI_OFF   0           // 512*2560 f16 = 2,621,440
#define WLO_OFF   2621440     // 2,621,440
#define PL_OFF    5242880     // 8*96000 f32 = 3,072,000
#define ALPHA_OFF 8314880     // 96000 f32 = 384,000
#define SEGI_OFF  8698880     // 96000 int2 = 768,000
#define SEGW_OFF  9466880     // 96000 float2 = 768,000
#define TOT_OFF   10234880    // 32 int

#define CS_SIZE  ((size_t)B_ * T_ * C_)
#define MASK_OFF CS_SIZE
#define LOSS_OFF (CS_SIZE + (size_t)B_ * T_)

// ---------------- W prep: [o][i][k] fp32 -> Whi/Wlo [o][k*512+i] f16 -------
__global__ __launch_bounds__(256) void w_prep_kernel(
    const float* __restrict__ W, f16* __restrict__ whi, f16* __restrict__ wlo)
{
    int idx = blockIdx.x * 256 + threadIdx.x;
    if (idx >= 512 * KW) return;
    int o = idx / KW;
    int c = idx - o * KW;
    int k = c >> 9, i = c & 511;
    float w = W[o * KW + i * 5 + k];
    f16 h = (f16)w;
    f16 l = (f16)((w - (float)h) * 2048.0f);
    whi[idx] = h;
    wlo[idx] = l;
}

// ---------------- conv+relu+linear partial via fp16x2 MFMA -----------------
// block: 128 t x 128 o, 256 threads = 4 waves (2m x 2n), wave = 64x64
#define LDA 72    // f16 per A row (64 + 8 pad) = 144 B
#define LDW 40    // f16 per W row (32 + 8 pad) = 80 B
#define A_ROWS 132

__global__ __launch_bounds__(256, 2) void conv_alpha_mfma(
    const float* __restrict__ hs, const f16* __restrict__ whi_g,
    const f16* __restrict__ wlo_g, const float* __restrict__ conv_b,
    const float* __restrict__ lin_w, float* __restrict__ pl)
{
    __shared__ f16 sm[2 * A_ROWS * LDA + 2 * 128 * LDW];  // 58,496 B
    f16* Ahi = sm;
    f16* Alo = sm + A_ROWS * LDA;
    f16* Whi = sm + 2 * A_ROWS * LDA;
    f16* Wlo = Whi + 128 * LDW;

    int tid = threadIdx.x;
    int bid = blockIdx.x;
    int nb  = bid & 3;
    int mtg = bid >> 2;        // 0..767
    int b   = mtg / 24;
    int mt  = mtg - b * 24;
    int t0  = mt * 128;

    int wid = tid >> 6, l = tid & 63;
    int wm = wid >> 1, wn = wid & 1;
    int l15 = l & 15, l4 = l >> 4;

    const float* hb = hs + (size_t)b * T_ * C_;
    int o0 = nb * 128;

    floatx4 acc1[4][4], acc2[4][4];
#pragma unroll
    for (int mf = 0; mf < 4; ++mf)
#pragma unroll
        for (int nf = 0; nf < 4; ++nf) {
            acc1[mf][nf] = (floatx4)0.f;
            acc2[mf][nf] = (floatx4)0.f;
        }

    for (int ic = 0; ic < 8; ++ic) {
        int i0 = ic * 64;
        __syncthreads();                    // prev compute done before A overwrite
        // stage A: hs rows [t0-2, t0+129] x [i0, i0+64) -> hi/lo f16
        for (int j = tid; j < A_ROWS * 16; j += 256) {
            int r = j >> 4, c4 = j & 15;
            int t = t0 - 2 + r;
            float4 v = make_float4(0.f, 0.f, 0.f, 0.f);
            if (t >= 0 && t < T_)
                v = *(const float4*)(hb + (size_t)t * C_ + i0 + c4 * 4);
            f16 h0 = (f16)v.x, h1 = (f16)v.y, h2 = (f16)v.z, h3 = (f16)v.w;
            half4 hh = {h0, h1, h2, h3};
            half4 ll = {(f16)((v.x - (float)h0) * 2048.f),
                        (f16)((v.y - (float)h1) * 2048.f),
                        (f16)((v.z - (float)h2) * 2048.f),
                        (f16)((v.w - (float)h3) * 2048.f)};
            int off = r * LDA + c4 * 4;
            *(half4*)(Ahi + off) = hh;
            *(half4*)(Alo + off) = ll;
        }
        for (int k = 0; k < 5; ++k) {
            for (int sub = 0; sub < 2; ++sub) {
                __syncthreads();            // prev compute done / A staged
                int i32 = i0 + sub * 32;
                for (int j = tid; j < 512; j += 256) {
                    int r = j >> 2, cg = j & 3;
                    size_t gidx = (size_t)(o0 + r) * KW + k * 512 + i32 + cg * 8;
                    half8 wh = *(const half8*)(whi_g + gidx);
                    half8 wl = *(const half8*)(wlo_g + gidx);
                    int off = r * LDW + cg * 8;
                    *(half8*)(Whi + off) = wh;
                    *(half8*)(Wlo + off) = wl;
                }
                __syncthreads();            // W staged
                half8 ah[4], al[4], bh[4], bl[4];
#pragma unroll
                for (int f = 0; f < 4; ++f) {
                    int ar = wm * 64 + f * 16 + l15 + k;
                    int aoff = ar * LDA + sub * 32 + l4 * 8;
                    ah[f] = *(const half8*)(Ahi + aoff);
                    al[f] = *(const half8*)(Alo + aoff);
                    int wr = wn * 64 + f * 16 + l15;
                    int woff = wr * LDW + l4 * 8;
                    bh[f] = *(const half8*)(Whi + woff);
                    bl[f] = *(const half8*)(Wlo + woff);
                }
#pragma unroll
                for (int mf = 0; mf < 4; ++mf)
#pragma unroll
                    for (int nf = 0; nf < 4; ++nf) {
                        acc1[mf][nf] = __builtin_amdgcn_mfma_f32_16x16x32_f16(
                            ah[mf], bh[nf], acc1[mf][nf], 0, 0, 0);
                        acc2[mf][nf] = __builtin_amdgcn_mfma_f32_16x16x32_f16(
                            al[mf], bh[nf], acc2[mf][nf], 0, 0, 0);
                        acc2[mf][nf] = __builtin_amdgcn_mfma_f32_16x16x32_f16(
                            ah[mf], bl[nf], acc2[mf][nf], 0, 0, 0);
                    }
            }
        }
    }

    // epilogue: c = acc1 + acc2/2048; relu(c+b)*lw; reduce over o (16 lanes)
    float cb[4], lw[4];
#pragma unroll
    for (int nf = 0; nf < 4; ++nf) {
        int o = o0 + wn * 64 + nf * 16 + l15;
        cb[nf] = conv_b[o];
        lw[nf] = lin_w[o];
    }
    float* plb = pl + (size_t)(nb * 2 + wn) * (B_ * T_) + b * T_;
#pragma unroll
    for (int mf = 0; mf < 4; ++mf) {
#pragma unroll
        for (int reg = 0; reg < 4; ++reg) {
            float v = 0.f;
#pragma unroll
            for (int nf = 0; nf < 4; ++nf) {
                float c = acc1[mf][nf][reg] + acc2[mf][nf][reg] * (1.0f / 2048.0f);
                v += fmaxf(c + cb[nf], 0.f) * lw[nf];
            }
            v += __shfl_xor(v, 1);
            v += __shfl_xor(v, 2);
            v += __shfl_xor(v, 4);
            v += __shfl_xor(v, 8);
            int trow = t0 + wm * 64 + mf * 16 + l4 * 4 + reg;
            if (l15 == reg && trow < T_) plb[trow] = v;
        }
    }
}

// ---------------- combine partials + sigmoid -> alpha ----------------------
__global__ __launch_bounds__(256) void alpha_combine_kernel(
    const float* __restrict__ pl, const float* __restrict__ lin_b,
    float* __restrict__ alpha)
{
    int idx = blockIdx.x * 256 + threadIdx.x;
    if (idx >= B_ * T_) return;
    float s = lin_b[0];
#pragma unroll
    for (int p = 0; p < 8; ++p) s += pl[(size_t)p * (B_ * T_) + idx];
    alpha[idx] = 1.f / (1.f + expf(-s));
}

// ---------------- sequential CIF scan (exact fp32 ref semantics) -----------
__global__ __launch_bounds__(64) void scan_kernel(
    float* __restrict__ alpha, const int* __restrict__ mask,
    int2* __restrict__ seg_i, float2* __restrict__ seg_w,
    int* __restrict__ total_rows, float* __restrict__ out_loss)
{
    int lane = threadIdx.x;
    float lsum = 0.f;
    if (lane < B_) {
        const float4* ap = (const float4*)(alpha + lane * T_);
        const int4*   mp = (const int4*)(mask + lane * T_);
        float* astore = alpha + lane * T_;
        int2*   si = seg_i + lane * T_;
        float2* sw = seg_w + lane * T_;

        float acc = 0.f, leftover = 0.f;
        int nf = 0, prev_t = -1;

        float4 c0 = ap[0], c1 = ap[1];
        int4   m0 = mp[0], m1 = mp[1];
        for (int tc = 0; tc < T_ / 8; ++tc) {
            float4 n0, n1; int4 nm0, nm1;
            if (tc + 1 < T_ / 8) {
                n0 = ap[(tc + 1) * 2]; n1 = ap[(tc + 1) * 2 + 1];
                nm0 = mp[(tc + 1) * 2]; nm1 = mp[(tc + 1) * 2 + 1];
            }
            float av[8] = {c0.x, c0.y, c0.z, c0.w, c1.x, c1.y, c1.z, c1.w};
            int   mv[8] = {m0.x, m0.y, m0.z, m0.w, m1.x, m1.y, m1.z, m1.w};
#pragma unroll
            for (int u = 0; u < 8; ++u) {
                int t = tc * 8 + u;
                float araw = av[u];
                lsum += araw;
                float a = (mv[u] != 0) ? araw : 0.f;
                astore[t] = a;
                float acc2 = acc + a;
                float a1 = THf - acc;
                if (acc2 >= THf) {
                    si[nf] = make_int2(prev_t, t);
                    sw[nf] = make_float2(leftover, a1);
                    float rem = a - a1;
                    leftover = rem;
                    acc = rem;
                    prev_t = t;
                    ++nf;
                } else {
                    acc = acc2;
                }
            }
            c0 = n0; c1 = n1; m0 = nm0; m1 = nm1;
        }
        int tot = nf;
        if (acc >= 0.5f * THf) {
            si[nf] = make_int2(prev_t, T_);
            sw[nf] = make_float2(leftover, 0.f);
            ++tot;
        }
        total_rows[lane] = tot;
        lsum = fabsf(lsum);
    }
#pragma unroll
    for (int off = 16; off >= 1; off >>= 1) lsum += __shfl_down(lsum, off);
    if (lane == 0) out_loss[0] = lsum;
}

// ---------------- segmented weighted emission + zero fill ------------------
__global__ __launch_bounds__(128) void emit_kernel(
    const float* __restrict__ hs, const float* __restrict__ alpha,
    const int2* __restrict__ seg_i, const float2* __restrict__ seg_w,
    const int* __restrict__ total_rows, float* __restrict__ out)
{
    int blk = blockIdx.x;
    int b = blk / T_;
    int r = blk % T_;
    int tid = threadIdx.x;

    float4* cs4 = (float4*)(out + ((size_t)b * T_ + r) * C_);
    float* maskp = out + MASK_OFF + (size_t)b * T_ + r;
    int tot = total_rows[b];

    if (r >= tot) {
        float4 z; z.x = 0.f; z.y = 0.f; z.z = 0.f; z.w = 0.f;
        cs4[tid] = z;
        if (tid == 0) *maskp = 0.f;
        return;
    }
    int2   si = seg_i[b * T_ + r];
    float2 sw = seg_w[b * T_ + r];
    const float4* hb = (const float4*)(hs + (size_t)b * T_ * C_);
    const float*  ab = alpha + b * T_;

    float4 acc; acc.x = 0.f; acc.y = 0.f; acc.z = 0.f; acc.w = 0.f;
    int ts = si.x, te = si.y;
    if (ts >= 0) {
        float4 h = hb[(size_t)ts * (C_ / 4) + tid];
        acc.x = sw.x * h.x; acc.y = sw.x * h.y; acc.z = sw.x * h.z; acc.w = sw.x * h.w;
    }
    for (int t = ts + 1; t < te; ++t) {
        float a = ab[t];
        float4 h = hb[(size_t)t * (C_ / 4) + tid];
        acc.x = fmaf(a, h.x, acc.x); acc.y = fmaf(a, h.y, acc.y);
        acc.z = fmaf(a, h.z, acc.z); acc.w = fmaf(a, h.w, acc.w);
    }
    if (te < T_) {
        float4 h = hb[(size_t)te * (C_ / 4) + tid];
        acc.x = fmaf(sw.y, h.x, acc.x); acc.y = fmaf(sw.y, h.y, acc.y);
        acc.z = fmaf(sw.y, h.z, acc.z); acc.w = fmaf(sw.y, h.w, acc.w);
    }
    cs4[tid] = acc;
    if (tid == 0) *maskp = 1.f;
}

// ---------------- launch ---------------------------------------------------
extern "C" void kernel_launch(void* const* d_in, const int* in_sizes, int n_in,
                              void* d_out, int out_size, void* d_ws, size_t ws_size,
                              hipStream_t stream)
{
    const float* hs     = (const float*)d_in[0];
    const int*   hmask  = (const int*)d_in[1];
    const float* conv_w = (const float*)d_in[2];
    const float* conv_b = (const float*)d_in[3];
    const float* lin_w  = (const float*)d_in[4];
    const float* lin_b  = (const float*)d_in[5];
    float* out = (float*)d_out;
    char*  ws  = (char*)d_ws;

    f16*    whi   = (f16*)(ws + WHI_OFF);
    f16*    wlo   = (f16*)(ws + WLO_OFF);
    float*  pl    = (float*)(ws + PL_OFF);
    float*  alpha = (float*)(ws + ALPHA_OFF);
    int2*   seg_i = (int2*)(ws + SEGI_OFF);
    float2* seg_w = (float2*)(ws + SEGW_OFF);
    int*    tot   = (int*)(ws + TOT_OFF);

    w_prep_kernel<<<(512 * KW + 255) / 256, 256, 0, stream>>>(conv_w, whi, wlo);
    conv_alpha_mfma<<<B_ * 24 * 4, 256, 0, stream>>>(hs, whi, wlo, conv_b, lin_w, pl);
    alpha_combine_kernel<<<(B_ * T_ + 255) / 256, 256, 0, stream>>>(pl, lin_b, alpha);
    scan_kernel<<<1, 64, 0, stream>>>(alpha, hmask, seg_i, seg_w, tot, out + LOSS_OFF);
    emit_kernel<<<B_ * T_, 128, 0, stream>>>(hs, alpha, seg_i, seg_w, tot, out);
}

// Round 3
// 971.273 us; speedup vs baseline: 5.2033x; 1.1651x over previous
//
#include <hip/hip_runtime.h>
#include <math.h>

#define B_ 32
#define T_ 3000
#define C_ 512
#define THf 1.0f
#define KW 2560   // 5*512 flattened conv K

typedef _Float16 f16;
typedef _Float16 half8 __attribute__((ext_vector_type(8)));
typedef float floatx4 __attribute__((ext_vector_type(4)));

#define GLOBAL_AS __attribute__((address_space(1)))
#define LDS_AS __attribute__((address_space(3)))

// ---- ws layout (bytes) ----
#define WHI_OFF   0           // 5*64*512*8 f16 = 2,621,440 B  layout [k][i8][o][ie]
#define WLO_OFF   2621440
#define PL_OFF    5242880     // 8*96000 f32
#define ALPHA_OFF 8314880
#define SEGI_OFF  8698880
#define SEGW_OFF  9466880
#define TOT_OFF   10234880

#define CS_SIZE  ((size_t)B_ * T_ * C_)
#define MASK_OFF CS_SIZE
#define LOSS_OFF (CS_SIZE + (size_t)B_ * T_)

// ---------------- W prep: [o][i][k] fp32 -> [k][i8][o][ie] f16 hi/lo -------
__global__ __launch_bounds__(256) void w_prep_kernel(
    const float* __restrict__ W, f16* __restrict__ whi, f16* __restrict__ wlo)
{
    int idx = blockIdx.x * 256 + threadIdx.x;
    if (idx >= 512 * KW) return;
    int ie = idx & 7;
    int o  = (idx >> 3) & 511;
    int i8 = (idx >> 12) & 63;
    int k  = idx >> 18;
    int i  = i8 * 8 + ie;
    float w = W[o * KW + i * 5 + k];
    f16 h = (f16)w;
    whi[idx] = h;
    wlo[idx] = (f16)((w - (float)h) * 2048.0f);
}

// ---------------- conv+relu+linear partial via fp16x2 MFMA -----------------
// block: 128 t x 128 o, 256 threads = 4 waves (2m x 2n), wave = 64x64 tile
#define A_ROWS 132
// LDS (f16 units): Ahi[132*64] @0, Alo @8448, Wb[buf][hi/lo][4*128*8] @16896
#define ALO_OFF_E  8448
#define WB_OFF_E   16896
#define WB_ARR_E   4096

__global__ __launch_bounds__(256, 2) void conv_alpha_mfma(
    const float* __restrict__ hs, const f16* __restrict__ whi_g,
    const f16* __restrict__ wlo_g, const float* __restrict__ conv_b,
    const float* __restrict__ lin_w, float* __restrict__ pl)
{
    __shared__ f16 sm[33280];   // 66,560 B
    f16* Ahi = sm;
    f16* Alo = sm + ALO_OFF_E;
    f16* Wb  = sm + WB_OFF_E;

    int tid = threadIdx.x;
    int bid = blockIdx.x;
    int nb  = bid & 3;
    int mtg = bid >> 2;
    int b   = mtg / 24;
    int mt  = mtg - b * 24;
    int t0  = mt * 128;

    int wid = tid >> 6, l = tid & 63;
    int wm = wid >> 1, wn = wid & 1;
    int l15 = l & 15, l4 = l >> 4;

    const float* hb = hs + (size_t)b * T_ * C_;
    int o0 = nb * 128;

    floatx4 acc1[4][4], acc2[4][4];
#pragma unroll
    for (int mf = 0; mf < 4; ++mf)
#pragma unroll
        for (int nf = 0; nf < 4; ++nf) {
            acc1[mf][nf] = (floatx4)0.f;
            acc2[mf][nf] = (floatx4)0.f;
        }

    // async W tile prefetch: step s -> Wb[s&1]; 16 regions of 1KB, wave wid does 4
    auto issue_w = [&](int s2) {
        int buf = s2 & 1;
        int ic2 = s2 / 10, kk2 = s2 % 10;
        int k2 = kk2 >> 1, sub2 = kk2 & 1;
        int i8b = ic2 * 8 + sub2 * 4;
#pragma unroll
        for (int rr = 0; rr < 4; ++rr) {
            int r = wid * 4 + rr;
            int arr = r >> 3, kc = (r >> 1) & 3, oh = r & 1;
            const f16* gsrc = (arr ? wlo_g : whi_g) +
                ((size_t)((k2 * 64 + i8b + kc) * 512 + o0 + oh * 64 + l)) * 8;
            f16* ldst = Wb + (buf * 2 + arr) * WB_ARR_E + (kc * 128 + oh * 64) * 8;
            __builtin_amdgcn_global_load_lds((const GLOBAL_AS void*)gsrc,
                                             (LDS_AS void*)ldst, 16, 0, 0);
        }
    };

    issue_w(0);   // prologue: W(step 0) -> buf 0

    for (int s = 0; s < 80; ++s) {
        int ic = s / 10, kk = s % 10;
        int k = kk >> 1, sub = kk & 1;
        int buf = s & 1;

        if (kk == 0) {
            // stage A tile for this ic: rows [t0-2, t0+129] x 64 i, hi/lo f16,
            // XOR-swizzled chunks (c ^ (r&7))
            int i0 = ic * 64;
            for (int j = tid; j < A_ROWS * 8; j += 256) {
                int r = j >> 3, c = j & 7;
                int t = t0 - 2 + r;
                float4 v0 = make_float4(0.f, 0.f, 0.f, 0.f);
                float4 v1 = v0;
                if ((unsigned)t < (unsigned)T_) {
                    const float4* p = (const float4*)(hb + (size_t)t * C_ + i0 + c * 8);
                    v0 = p[0]; v1 = p[1];
                }
                float vv[8] = {v0.x, v0.y, v0.z, v0.w, v1.x, v1.y, v1.z, v1.w};
                half8 hh, ll;
#pragma unroll
                for (int q = 0; q < 8; ++q) {
                    f16 x = (f16)vv[q];
                    hh[q] = x;
                    ll[q] = (f16)((vv[q] - (float)x) * 2048.f);
                }
                int off = r * 64 + (c ^ (r & 7)) * 8;
                *(half8*)(Ahi + off) = hh;
                *(half8*)(Alo + off) = ll;
            }
            __syncthreads();   // A staged; also drains W(s) prefetch (vmcnt)
        }

        if (s + 1 < 80) issue_w(s + 1);   // async, lands in buf^1

        // fragment reads
        half8 ah[4], al[4], bh[4], bl[4];
#pragma unroll
        for (int f = 0; f < 4; ++f) {
            int ar = wm * 64 + f * 16 + l15 + k;
            int aoff = ar * 64 + ((((sub << 2) | l4) ^ (ar & 7)) << 3);
            ah[f] = *(const half8*)(Ahi + aoff);
            al[f] = *(const half8*)(Alo + aoff);
            int wrow = l4 * 128 + wn * 64 + f * 16 + l15;
            bh[f] = *(const half8*)(Wb + (buf * 2 + 0) * WB_ARR_E + wrow * 8);
            bl[f] = *(const half8*)(Wb + (buf * 2 + 1) * WB_ARR_E + wrow * 8);
        }
        __builtin_amdgcn_s_setprio(1);
#pragma unroll
        for (int mf = 0; mf < 4; ++mf)
#pragma unroll
            for (int nf = 0; nf < 4; ++nf) {
                acc1[mf][nf] = __builtin_amdgcn_mfma_f32_16x16x32_f16(
                    ah[mf], bh[nf], acc1[mf][nf], 0, 0, 0);
                acc2[mf][nf] = __builtin_amdgcn_mfma_f32_16x16x32_f16(
                    al[mf], bh[nf], acc2[mf][nf], 0, 0, 0);
                acc2[mf][nf] = __builtin_amdgcn_mfma_f32_16x16x32_f16(
                    ah[mf], bl[nf], acc2[mf][nf], 0, 0, 0);
            }
        __builtin_amdgcn_s_setprio(0);
        __syncthreads();   // frag reads done + W(s+1) landed
    }

    // epilogue: c = acc1 + acc2/2048; relu(c+b)*lw; reduce over 16 o-lanes
    float cb[4], lw[4];
#pragma unroll
    for (int nf = 0; nf < 4; ++nf) {
        int o = o0 + wn * 64 + nf * 16 + l15;
        cb[nf] = conv_b[o];
        lw[nf] = lin_w[o];
    }
    float* plb = pl + (size_t)(nb * 2 + wn) * (B_ * T_) + b * T_;
#pragma unroll
    for (int mf = 0; mf < 4; ++mf) {
#pragma unroll
        for (int reg = 0; reg < 4; ++reg) {
            float v = 0.f;
#pragma unroll
            for (int nf = 0; nf < 4; ++nf) {
                float c = acc1[mf][nf][reg] + acc2[mf][nf][reg] * (1.0f / 2048.0f);
                v += fmaxf(c + cb[nf], 0.f) * lw[nf];
            }
            v += __shfl_xor(v, 1);
            v += __shfl_xor(v, 2);
            v += __shfl_xor(v, 4);
            v += __shfl_xor(v, 8);
            int trow = t0 + wm * 64 + mf * 16 + l4 * 4 + reg;
            if (l15 == reg && trow < T_) plb[trow] = v;
        }
    }
}

// ---------------- combine partials + sigmoid -> alpha ----------------------
__global__ __launch_bounds__(256) void alpha_combine_kernel(
    const float* __restrict__ pl, const float* __restrict__ lin_b,
    float* __restrict__ alpha)
{
    int idx = blockIdx.x * 256 + threadIdx.x;
    if (idx >= B_ * T_) return;
    float s = lin_b[0];
#pragma unroll
    for (int p = 0; p < 8; ++p) s += pl[(size_t)p * (B_ * T_) + idx];
    alpha[idx] = 1.f / (1.f + expf(-s));
}

// ---------------- sequential CIF scan (exact fp32 ref semantics) -----------
__global__ __launch_bounds__(64) void scan_kernel(
    float* __restrict__ alpha, const int* __restrict__ mask,
    int2* __restrict__ seg_i, float2* __restrict__ seg_w,
    int* __restrict__ total_rows, float* __restrict__ out_loss)
{
    int lane = threadIdx.x;
    float lsum = 0.f;
    if (lane < B_) {
        const float4* ap = (const float4*)(alpha + lane * T_);
        const int4*   mp = (const int4*)(mask + lane * T_);
        float* astore = alpha + lane * T_;
        int2*   si = seg_i + lane * T_;
        float2* sw = seg_w + lane * T_;

        float acc = 0.f, leftover = 0.f;
        int nf = 0, prev_t = -1;

        float4 c0 = ap[0], c1 = ap[1];
        int4   m0 = mp[0], m1 = mp[1];
        for (int tc = 0; tc < T_ / 8; ++tc) {
            float4 n0, n1; int4 nm0, nm1;
            if (tc + 1 < T_ / 8) {
                n0 = ap[(tc + 1) * 2]; n1 = ap[(tc + 1) * 2 + 1];
                nm0 = mp[(tc + 1) * 2]; nm1 = mp[(tc + 1) * 2 + 1];
            }
            float av[8] = {c0.x, c0.y, c0.z, c0.w, c1.x, c1.y, c1.z, c1.w};
            int   mv[8] = {m0.x, m0.y, m0.z, m0.w, m1.x, m1.y, m1.z, m1.w};
#pragma unroll
            for (int u = 0; u < 8; ++u) {
                int t = tc * 8 + u;
                float araw = av[u];
                lsum += araw;
                float a = (mv[u] != 0) ? araw : 0.f;
                astore[t] = a;
                float acc2 = acc + a;
                float a1 = THf - acc;
                if (acc2 >= THf) {
                    si[nf] = make_int2(prev_t, t);
                    sw[nf] = make_float2(leftover, a1);
                    float rem = a - a1;
                    leftover = rem;
                    acc = rem;
                    prev_t = t;
                    ++nf;
                } else {
                    acc = acc2;
                }
            }
            c0 = n0; c1 = n1; m0 = nm0; m1 = nm1;
        }
        int tot = nf;
        if (acc >= 0.5f * THf) {
            si[nf] = make_int2(prev_t, T_);
            sw[nf] = make_float2(leftover, 0.f);
            ++tot;
        }
        total_rows[lane] = tot;
        lsum = fabsf(lsum);
    }
#pragma unroll
    for (int off = 16; off >= 1; off >>= 1) lsum += __shfl_down(lsum, off);
    if (lane == 0) out_loss[0] = lsum;
}

// ---------------- segmented weighted emission + zero fill ------------------
__global__ __launch_bounds__(128) void emit_kernel(
    const float* __restrict__ hs, const float* __restrict__ alpha,
    const int2* __restrict__ seg_i, const float2* __restrict__ seg_w,
    const int* __restrict__ total_rows, float* __restrict__ out)
{
    int blk = blockIdx.x;
    int b = blk / T_;
    int r = blk % T_;
    int tid = threadIdx.x;

    float4* cs4 = (float4*)(out + ((size_t)b * T_ + r) * C_);
    float* maskp = out + MASK_OFF + (size_t)b * T_ + r;
    int tot = total_rows[b];

    if (r >= tot) {
        float4 z; z.x = 0.f; z.y = 0.f; z.z = 0.f; z.w = 0.f;
        cs4[tid] = z;
        if (tid == 0) *maskp = 0.f;
        return;
    }
    int2   si = seg_i[b * T_ + r];
    float2 sw = seg_w[b * T_ + r];
    const float4* hb = (const float4*)(hs + (size_t)b * T_ * C_);
    const float*  ab = alpha + b * T_;

    float4 acc; acc.x = 0.f; acc.y = 0.f; acc.z = 0.f; acc.w = 0.f;
    int ts = si.x, te = si.y;
    if (ts >= 0) {
        float4 h = hb[(size_t)ts * (C_ / 4) + tid];
        acc.x = sw.x * h.x; acc.y = sw.x * h.y; acc.z = sw.x * h.z; acc.w = sw.x * h.w;
    }
    for (int t = ts + 1; t < te; ++t) {
        float a = ab[t];
        float4 h = hb[(size_t)t * (C_ / 4) + tid];
        acc.x = fmaf(a, h.x, acc.x); acc.y = fmaf(a, h.y, acc.y);
        acc.z = fmaf(a, h.z, acc.z); acc.w = fmaf(a, h.w, acc.w);
    }
    if (te < T_) {
        float4 h = hb[(size_t)te * (C_ / 4) + tid];
        acc.x = fmaf(sw.y, h.x, acc.x); acc.y = fmaf(sw.y, h.y, acc.y);
        acc.z = fmaf(sw.y, h.z, acc.z); acc.w = fmaf(sw.y, h.w, acc.w);
    }
    cs4[tid] = acc;
    if (tid == 0) *maskp = 1.f;
}

// ---------------- launch ---------------------------------------------------
extern "C" void kernel_launch(void* const* d_in, const int* in_sizes, int n_in,
                              void* d_out, int out_size, void* d_ws, size_t ws_size,
                              hipStream_t stream)
{
    const float* hs     = (const float*)d_in[0];
    const int*   hmask  = (const int*)d_in[1];
    const float* conv_w = (const float*)d_in[2];
    const float* conv_b = (const float*)d_in[3];
    const float* lin_w  = (const float*)d_in[4];
    const float* lin_b  = (const float*)d_in[5];
    float* out = (float*)d_out;
    char*  ws  = (char*)d_ws;

    f16*    whi   = (f16*)(ws + WHI_OFF);
    f16*    wlo   = (f16*)(ws + WLO_OFF);
    float*  pl    = (float*)(ws + PL_OFF);
    float*  alpha = (float*)(ws + ALPHA_OFF);
    int2*   seg_i = (int2*)(ws + SEGI_OFF);
    float2* seg_w = (float2*)(ws + SEGW_OFF);
    int*    tot   = (int*)(ws + TOT_OFF);

    w_prep_kernel<<<(512 * KW + 255) / 256, 256, 0, stream>>>(conv_w, whi, wlo);
    conv_alpha_mfma<<<B_ * 24 * 4, 256, 0, stream>>>(hs, whi, wlo, conv_b, lin_w, pl);
    alpha_combine_kernel<<<(B_ * T_ + 255) / 256, 256, 0, stream>>>(pl, lin_b, alpha);
    scan_kernel<<<1, 64, 0, stream>>>(alpha, hmask, seg_i, seg_w, tot, out + LOSS_OFF);
    emit_kernel<<<B_ * T_, 128, 0, stream>>>(hs, alpha, seg_i, seg_w, tot, out);
}